// Round 1
// baseline (586.695 us; speedup 1.0000x reference)
//
#include <hip/hip_runtime.h>
#include <hip/hip_bf16.h>

typedef _Float16 half8 __attribute__((ext_vector_type(8)));
typedef float f32x4 __attribute__((ext_vector_type(4)));

#define B_TOTAL 32768
#define T 7
#define F 36
#define U 256
#define G4 1024
#define BM 64
#define KC 10          // K chunks of 32: kc 0..7 = h (K=256), kc 8..9 = x (F=36 padded to 64)
#define KPACK 32
#define H_STRIDE 264   // halves; 264*2=528 B = 16B-aligned rows
#define X_STRIDE 72    // halves; 72*2=144 B = 16B-aligned rows

// Pack W = [Wr (256 rows); Wk (36 rows); zeros (28 rows)] into fragment-native
// layout Wq[kc][n][kin] fp16, so a B-fragment is one coalesced 16B load/lane.
__global__ __launch_bounds__(1024) void pack_w(const float* __restrict__ Wr,
                                               const float* __restrict__ Wk,
                                               _Float16* __restrict__ Wq) {
    const int kc = blockIdx.x;        // 0..KC-1
    const int n  = threadIdx.x;       // 0..1023
    _Float16* dst = Wq + ((size_t)kc * G4 + n) * KPACK;
    #pragma unroll
    for (int kin = 0; kin < KPACK; ++kin) {
        int k = kc * KPACK + kin;     // global K: 0..255 -> Wr, 256..291 -> Wk, else 0
        float v = 0.f;
        if (k < U)          v = Wr[(size_t)k * G4 + n];
        else if (k < U + F) v = Wk[(size_t)(k - U) * G4 + n];
        dst[kin] = (_Float16)v;
    }
}

__device__ __forceinline__ float fast_sigmoid(float x) {
    return __builtin_amdgcn_rcpf(1.f + __expf(-x));
}
__device__ __forceinline__ float fast_tanh(float x) {
    return 1.f - 2.f * __builtin_amdgcn_rcpf(1.f + __expf(2.f * x));
}

// Persistent LSTM: one block owns BM=64 batch rows for all T=7 steps.
// Wave w (of 16) owns u-range [16w,16w+16) x 4 gates x all 64 rows.
__global__ __launch_bounds__(1024) void lstm_kernel(
    const float* __restrict__ x,   // [B,T,F]
    const float* __restrict__ h0,  // [B,U]
    const float* __restrict__ c0,  // [B,U]
    const _Float16* __restrict__ Wq, // packed [KC][G4][KPACK]
    const float* __restrict__ bias_g, // [G4]
    float* __restrict__ out)       // [B,T,U]
{
    __shared__ __align__(16) _Float16 hA[BM * H_STRIDE];
    __shared__ __align__(16) _Float16 xA[BM * X_STRIDE];

    const int tid  = threadIdx.x;
    const int lane = tid & 63;
    const int w    = tid >> 6;     // wave id = u-tile
    const int l15  = lane & 15;
    const int q    = lane >> 4;    // 0..3
    const int u0   = w * 16;
    const int b0   = blockIdx.x * BM;

    // --- stage h0 -> LDS fp16 (block region is contiguous) ---
    for (int i = tid; i < BM * U; i += 1024) {
        int m = i >> 8, u = i & 255;
        hA[m * H_STRIDE + u] = (_Float16)h0[(size_t)b0 * U + i];
    }
    // --- zero x padding cols F..63 (written once, stays zero) ---
    for (int i = tid; i < BM * (64 - F); i += 1024) {
        int m = i / (64 - F), f = i % (64 - F);
        xA[m * X_STRIDE + F + f] = (_Float16)0.f;
    }
    // --- stage x slice for t=0 ---
    for (int i = tid; i < BM * F; i += 1024) {
        int m = i / F, f = i % F;
        xA[m * X_STRIDE + f] = (_Float16)x[((size_t)(b0 + m) * T) * F + f];
    }
    // --- c0 into registers: lane holds (u = u0+l15) for rows mt*16+q*4+r ---
    float c[16];
    #pragma unroll
    for (int mt = 0; mt < 4; ++mt)
        #pragma unroll
        for (int r = 0; r < 4; ++r) {
            int row = mt * 16 + q * 4 + r;
            c[mt * 4 + r] = c0[(size_t)(b0 + row) * U + u0 + l15];
        }
    // --- bias per gate (same column all 4 rows) ---
    float bv[4];
    #pragma unroll
    for (int g = 0; g < 4; ++g) bv[g] = bias_g[g * U + u0 + l15];

    __syncthreads();

    for (int t = 0; t < T; ++t) {
        f32x4 acc[4][4];   // [m_tile][gate]
        #pragma unroll
        for (int mt = 0; mt < 4; ++mt)
            #pragma unroll
            for (int g = 0; g < 4; ++g)
                acc[mt][g] = (f32x4){bv[g], bv[g], bv[g], bv[g]};

        // prefetch next step's x slice into registers (hidden under K-loop)
        int tn = (t + 1 < T) ? t + 1 : t;
        float xp0, xp1, xp2 = 0.f;
        {
            int i = tid;        int m = i / F, f = i % F;
            xp0 = x[((size_t)(b0 + m) * T + tn) * F + f];
        }
        {
            int i = tid + 1024; int m = i / F, f = i % F;
            xp1 = x[((size_t)(b0 + m) * T + tn) * F + f];
        }
        if (tid < BM * F - 2048) {
            int i = tid + 2048; int m = i / F, f = i % F;
            xp2 = x[((size_t)(b0 + m) * T + tn) * F + f];
        }

        // --- K loop: z[64,1024] = h@Wr + x_t@Wk + b ---
        #pragma unroll 2
        for (int kc = 0; kc < KC; ++kc) {
            half8 bf[4];
            #pragma unroll
            for (int g = 0; g < 4; ++g) {
                size_t off = ((size_t)kc * G4 + g * U + u0 + l15) * KPACK + q * 8;
                bf[g] = *(const half8*)(Wq + off);
            }
            #pragma unroll
            for (int mt = 0; mt < 4; ++mt) {
                half8 af;
                if (kc < 8)
                    af = *(const half8*)&hA[(mt * 16 + l15) * H_STRIDE + kc * 32 + q * 8];
                else
                    af = *(const half8*)&xA[(mt * 16 + l15) * X_STRIDE + (kc - 8) * 32 + q * 8];
                #pragma unroll
                for (int g = 0; g < 4; ++g)
                    acc[mt][g] = __builtin_amdgcn_mfma_f32_16x16x32_f16(af, bf[g], acc[mt][g], 0, 0, 0);
            }
        }

        // --- gates: i,f,g,o for (row,u) all live in the same lane ---
        float hnew[16];
        #pragma unroll
        for (int mt = 0; mt < 4; ++mt)
            #pragma unroll
            for (int r = 0; r < 4; ++r) {
                float zi = acc[mt][0][r];
                float zf = acc[mt][1][r];
                float zg = acc[mt][2][r];
                float zo = acc[mt][3][r];
                float ig = fast_sigmoid(zi);
                float fg = fast_sigmoid(zf);
                float gg = fast_tanh(zg);
                float og = fast_sigmoid(zo);
                float cn = fg * c[mt * 4 + r] + ig * gg;
                c[mt * 4 + r] = cn;
                hnew[mt * 4 + r] = og * fast_tanh(cn);
            }

        __syncthreads();   // all waves done reading hA/xA for step t

        // write h_new to LDS (fp16, next step's A) and to out (fp32)
        #pragma unroll
        for (int mt = 0; mt < 4; ++mt)
            #pragma unroll
            for (int r = 0; r < 4; ++r) {
                int row = mt * 16 + q * 4 + r;
                float hv = hnew[mt * 4 + r];
                hA[row * H_STRIDE + u0 + l15] = (_Float16)hv;
                out[((size_t)(b0 + row) * T + t) * U + u0 + l15] = hv;
            }
        // stage prefetched x for t+1
        if (t + 1 < T) {
            { int i = tid;        int m = i / F, f = i % F; xA[m * X_STRIDE + f] = (_Float16)xp0; }
            { int i = tid + 1024; int m = i / F, f = i % F; xA[m * X_STRIDE + f] = (_Float16)xp1; }
            if (tid < BM * F - 2048) {
                int i = tid + 2048; int m = i / F, f = i % F;
                xA[m * X_STRIDE + f] = (_Float16)xp2;
            }
        }
        __syncthreads();
    }
}

extern "C" void kernel_launch(void* const* d_in, const int* in_sizes, int n_in,
                              void* d_out, int out_size, void* d_ws, size_t ws_size,
                              hipStream_t stream) {
    const float* x  = (const float*)d_in[0];
    const float* h0 = (const float*)d_in[1];
    const float* c0 = (const float*)d_in[2];
    const float* Wk = (const float*)d_in[3];
    const float* Wr = (const float*)d_in[4];
    const float* b  = (const float*)d_in[5];
    float* out = (float*)d_out;

    _Float16* Wq = (_Float16*)d_ws;   // KC*G4*KPACK*2 = 640 KB

    pack_w<<<KC, 1024, 0, stream>>>(Wr, Wk, Wq);
    lstm_kernel<<<B_TOTAL / BM, 1024, 0, stream>>>(x, h0, c0, Wq, b, out);
}

// Round 2
// 517.176 us; speedup vs baseline: 1.1344x; 1.1344x over previous
//
#include <hip/hip_runtime.h>
#include <hip/hip_bf16.h>

typedef _Float16 half8 __attribute__((ext_vector_type(8)));
typedef float f32x4 __attribute__((ext_vector_type(4)));

#define B_TOTAL 32768
#define T 7
#define F 36
#define U 256
#define G4 1024
#define BM 64
#define KC 10          // K chunks of 32: kc 0..7 = h (K=256), kc 8..9 = x (F=36 padded to 64)
#define KPACK 32
#define H_STRIDE 264   // halves; 264*2=528 B = 16B-aligned rows
#define X_STRIDE 72    // halves; 72*2=144 B = 16B-aligned rows

// Pack W = [Wr (256 rows); Wk (36 rows); zeros (28 rows)] into fragment-native
// layout Wq[kc][n][kin] fp16. Grid KC*4 so pack runs wide (40 blocks).
__global__ __launch_bounds__(1024) void pack_w(const float* __restrict__ Wr,
                                               const float* __restrict__ Wk,
                                               _Float16* __restrict__ Wq) {
    const int kc   = blockIdx.x >> 2;
    const int kin0 = (blockIdx.x & 3) * 8;
    const int n    = threadIdx.x;
    _Float16* dst = Wq + ((size_t)kc * G4 + n) * KPACK + kin0;
    #pragma unroll
    for (int j = 0; j < 8; ++j) {
        int k = kc * KPACK + kin0 + j;
        float v = 0.f;
        if (k < U)          v = Wr[(size_t)k * G4 + n];
        else if (k < U + F) v = Wk[(size_t)(k - U) * G4 + n];
        dst[j] = (_Float16)v;
    }
}

__device__ __forceinline__ float fast_sigmoid(float x) {
    return __builtin_amdgcn_rcpf(1.f + __expf(-x));
}
__device__ __forceinline__ float fast_tanh(float x) {
    return 1.f - 2.f * __builtin_amdgcn_rcpf(1.f + __expf(2.f * x));
}

// Persistent LSTM: one block owns BM=64 batch rows for all T=7 steps.
// Wave w (of 16) owns u-range [16w,16w+16) x 4 gates x all 64 rows.
__global__ __launch_bounds__(1024) void lstm_kernel(
    const float* __restrict__ x,   // [B,T,F]
    const float* __restrict__ h0,  // [B,U]
    const float* __restrict__ c0,  // [B,U]
    const _Float16* __restrict__ Wq, // packed [KC][G4][KPACK]
    const float* __restrict__ bias_g, // [G4]
    float* __restrict__ out)       // [B,T,U]
{
    __shared__ __align__(16) _Float16 hA[BM * H_STRIDE];
    __shared__ __align__(16) _Float16 xA[BM * X_STRIDE];

    const int tid  = threadIdx.x;
    const int lane = tid & 63;
    const int w    = tid >> 6;     // wave id = u-tile
    const int l15  = lane & 15;
    const int q    = lane >> 4;    // 0..3
    const int u0   = w * 16;
    const int b0   = blockIdx.x * BM;

    // --- stage h0 -> LDS fp16 (block region is contiguous) ---
    for (int i = tid; i < BM * U; i += 1024) {
        int m = i >> 8, u = i & 255;
        hA[m * H_STRIDE + u] = (_Float16)h0[(size_t)b0 * U + i];
    }
    // --- zero x padding cols F..63 (written once, stays zero) ---
    for (int i = tid; i < BM * (64 - F); i += 1024) {
        int m = i / (64 - F), f = i % (64 - F);
        xA[m * X_STRIDE + F + f] = (_Float16)0.f;
    }
    // --- stage x slice for t=0 ---
    for (int i = tid; i < BM * F; i += 1024) {
        int m = i / F, f = i % F;
        xA[m * X_STRIDE + f] = (_Float16)x[((size_t)(b0 + m) * T) * F + f];
    }
    // --- c0 into registers: lane holds (u = u0+l15) for rows mt*16+q*4+r ---
    float c[16];
    #pragma unroll
    for (int mt = 0; mt < 4; ++mt)
        #pragma unroll
        for (int r = 0; r < 4; ++r) {
            int row = mt * 16 + q * 4 + r;
            c[mt * 4 + r] = c0[(size_t)(b0 + row) * U + u0 + l15];
        }
    // --- bias per gate (same column all 4 rows) ---
    float bv[4];
    #pragma unroll
    for (int g = 0; g < 4; ++g) bv[g] = bias_g[g * U + u0 + l15];

    __syncthreads();

    for (int t = 0; t < T; ++t) {
        f32x4 acc[4][4];   // [m_tile][gate]
        #pragma unroll
        for (int mt = 0; mt < 4; ++mt)
            #pragma unroll
            for (int g = 0; g < 4; ++g)
                acc[mt][g] = (f32x4){bv[g], bv[g], bv[g], bv[g]};

        // prefetch next step's x slice into registers (hidden under K-loop)
        float xp0 = 0.f, xp1 = 0.f, xp2 = 0.f;
        if (t + 1 < T) {
            {
                int i = tid;        int m = i / F, f = i % F;
                xp0 = x[((size_t)(b0 + m) * T + t + 1) * F + f];
            }
            {
                int i = tid + 1024; int m = i / F, f = i % F;
                xp1 = x[((size_t)(b0 + m) * T + t + 1) * F + f];
            }
            if (tid < BM * F - 2048) {
                int i = tid + 2048; int m = i / F, f = i % F;
                xp2 = x[((size_t)(b0 + m) * T + t + 1) * F + f];
            }
        }

        // --- K loop: z[64,1024] = h@Wr + x_t@Wk + b ---
        #pragma unroll 2
        for (int kc = 0; kc < KC; ++kc) {
            half8 bf[4];
            #pragma unroll
            for (int g = 0; g < 4; ++g) {
                size_t off = ((size_t)kc * G4 + g * U + u0 + l15) * KPACK + q * 8;
                bf[g] = *(const half8*)(Wq + off);
            }
            #pragma unroll
            for (int mt = 0; mt < 4; ++mt) {
                half8 af;
                if (kc < 8)
                    af = *(const half8*)&hA[(mt * 16 + l15) * H_STRIDE + kc * 32 + q * 8];
                else
                    af = *(const half8*)&xA[(mt * 16 + l15) * X_STRIDE + (kc - 8) * 32 + q * 8];
                #pragma unroll
                for (int g = 0; g < 4; ++g)
                    acc[mt][g] = __builtin_amdgcn_mfma_f32_16x16x32_f16(af, bf[g], acc[mt][g], 0, 0, 0);
            }
        }

        // --- gates: i,f,g,o for (row,u) all live in the same lane ---
        float hnew[16];
        #pragma unroll
        for (int mt = 0; mt < 4; ++mt)
            #pragma unroll
            for (int r = 0; r < 4; ++r) {
                float zi = acc[mt][0][r];
                float zf = acc[mt][1][r];
                float zg = acc[mt][2][r];
                float zo = acc[mt][3][r];
                float ig = fast_sigmoid(zi);
                float fg = fast_sigmoid(zf);
                float gg = fast_tanh(zg);
                float og = fast_sigmoid(zo);
                float cn = fg * c[mt * 4 + r] + ig * gg;
                c[mt * 4 + r] = cn;
                hnew[mt * 4 + r] = og * fast_tanh(cn);
            }

        __syncthreads();   // all waves done reading hA/xA for step t

        // write h_new to LDS (fp16; feeds next step's A AND the coalesced out-store)
        #pragma unroll
        for (int mt = 0; mt < 4; ++mt)
            #pragma unroll
            for (int r = 0; r < 4; ++r) {
                int row = mt * 16 + q * 4 + r;
                hA[row * H_STRIDE + u0 + l15] = (_Float16)hnew[mt * 4 + r];
            }
        // stage prefetched x for t+1
        if (t + 1 < T) {
            { int i = tid;        int m = i / F, f = i % F; xA[m * X_STRIDE + f] = (_Float16)xp0; }
            { int i = tid + 1024; int m = i / F, f = i % F; xA[m * X_STRIDE + f] = (_Float16)xp1; }
            if (tid < BM * F - 2048) {
                int i = tid + 2048; int m = i / F, f = i % F;
                xA[m * X_STRIDE + f] = (_Float16)xp2;
            }
        }
        __syncthreads();

        // --- coalesced out-store: read h_t back from hA as half8, store 2x float4.
        // Consecutive tids cover consecutive 32B -> full 128B lines, no write-allocate RMW.
        // Fire-and-forget: overlaps the next step's K-loop. Safe: next hA write is
        // after the next step's first barrier, which orders it after these reads.
        #pragma unroll
        for (int rb = 0; rb < 2; ++rb) {
            int j   = tid + rb * 1024;      // 0..2047 chunks of 8 floats
            int row = j >> 5;
            int uo  = (j & 31) * 8;
            half8 hv = *(const half8*)&hA[row * H_STRIDE + uo];
            f32x4 lo = { (float)hv[0], (float)hv[1], (float)hv[2], (float)hv[3] };
            f32x4 hi = { (float)hv[4], (float)hv[5], (float)hv[6], (float)hv[7] };
            float* dst = out + ((size_t)(b0 + row) * T + t) * U + uo;
            *(f32x4*)dst       = lo;
            *(f32x4*)(dst + 4) = hi;
        }
    }
}

extern "C" void kernel_launch(void* const* d_in, const int* in_sizes, int n_in,
                              void* d_out, int out_size, void* d_ws, size_t ws_size,
                              hipStream_t stream) {
    const float* x  = (const float*)d_in[0];
    const float* h0 = (const float*)d_in[1];
    const float* c0 = (const float*)d_in[2];
    const float* Wk = (const float*)d_in[3];
    const float* Wr = (const float*)d_in[4];
    const float* b  = (const float*)d_in[5];
    float* out = (float*)d_out;

    _Float16* Wq = (_Float16*)d_ws;   // KC*G4*KPACK*2 = 640 KB

    pack_w<<<KC * 4, 1024, 0, stream>>>(Wr, Wk, Wq);
    lstm_kernel<<<B_TOTAL / BM, 1024, 0, stream>>>(x, h0, c0, Wq, b, out);
}